// Round 7
// baseline (183.992 us; speedup 1.0000x reference)
//
#include <hip/hip_runtime.h>
#include <hip/hip_cooperative_groups.h>

namespace cg = cooperative_groups;

#define NTHREADS 256
#define EPT      8              // elements per thread per chunk
#define CHUNK    (NTHREADS*EPT) // 2048 elements
#define ROWS     16
#define NBLOCKS_C 512           // cooperative grid (2 blocks/CU needed)
#define BPRB_C   (NBLOCKS_C/ROWS) // 32 blocks per row
#define NBLOCKS_F 1024          // fallback grid (R6-proven)
#define BPRB_F   (NBLOCKS_F/ROWS) // 64 blocks per row

#define C_TREND   0.6f
#define C_DETAIL  0.85f
#define C_SPIKE_T 3.5f
#define C_SPIKE_D 0.35f
#define C_EPS     1e-6f

typedef float vfloat4 __attribute__((ext_vector_type(4)));

__device__ __forceinline__ float reflect_load(const float* __restrict__ rp, int g, int L) {
    if (g < 0) g = -g;
    else if (g >= L) g = 2 * L - 2 - g;
    return rp[g];
}

// Deterministic block reduce of (s,s2); totals valid in ALL threads.
__device__ __forceinline__ void blk_reduce2(double& s, double& s2) {
    #pragma unroll
    for (int off = 32; off > 0; off >>= 1) {
        s  += __shfl_xor(s, off);
        s2 += __shfl_xor(s2, off);
    }
    __shared__ double lds[8];
    int wid = threadIdx.x >> 6, lane = threadIdx.x & 63;
    __syncthreads();                       // guard lds reuse
    if (lane == 0) { lds[2*wid] = s; lds[2*wid+1] = s2; }
    __syncthreads();
    s  = lds[0] + lds[2] + lds[4] + lds[6];
    s2 = lds[1] + lds[3] + lds[5] + lds[7];
}

// thr from NPART (s,s2) pairs; identical value in every block (fixed order).
// ATOMIC=true uses agent-scope relaxed loads (L2-bypass) for cross-XCD safety
// within a single cooperative kernel.
template<int NPART, bool ATOMIC>
__device__ __forceinline__ float compute_thr(const double* __restrict__ prow, int L) {
    __shared__ float thr_s;
    __syncthreads();                       // guard thr_s reuse
    if (threadIdx.x < NPART) {
        double s, s2;
        if (ATOMIC) {
            s  = __hip_atomic_load(prow + 2*threadIdx.x + 0, __ATOMIC_RELAXED, __HIP_MEMORY_SCOPE_AGENT);
            s2 = __hip_atomic_load(prow + 2*threadIdx.x + 1, __ATOMIC_RELAXED, __HIP_MEMORY_SCOPE_AGENT);
        } else {
            s  = prow[2*threadIdx.x + 0];
            s2 = prow[2*threadIdx.x + 1];
        }
        #pragma unroll
        for (int off = NPART/2; off > 0; off >>= 1) {
            s  += __shfl_xor(s, off);
            s2 += __shfl_xor(s2, off);
        }
        if (threadIdx.x == 0) {
            double n = (double)L;
            double var = (s2 - s * s / n) / (n - 1.0);
            float stdv = (float)sqrt(fmax(var, 0.0));
            thr_s = fmaxf(stdv, C_EPS) * C_SPIKE_T;
        }
    }
    __syncthreads();
    return thr_s;
}

// scalar (boundary) pass-1 output at logical position p (reflect-indexed)
__device__ float xp1_scalar(const float* __restrict__ rp, int L, int p, float thr) {
    if (p < 0) p = -p;
    else if (p >= L) p = 2 * L - 2 - p;
    float s5 = 0.f, s11 = 0.f;
    #pragma unroll
    for (int k = -5; k <= 5; ++k) {
        float v = reflect_load(rp, p + k, L);
        s11 += v;
        if (k >= -2 && k <= 2) s5 += v;
    }
    float local = s5 * 0.2f;
    float trend = s11 * (1.0f / 11.0f);
    float r = rp[p] - local;
    r = (fabsf(r) > thr) ? r * C_SPIKE_D : r;
    return (1.0f - C_TREND) * local + C_TREND * trend + C_DETAIL * r;
}

// ---- per-chunk phase bodies (identical math to the R6-verified kernels) ----

__device__ __forceinline__ void chunkA(const float* __restrict__ rp, int o, int L,
                                       double& s, double& s2) {
    float w[16];
    if (o >= 4 && o + 12 <= L) {
        const float4* p = reinterpret_cast<const float4*>(rp + o - 4);
        #pragma unroll
        for (int j = 0; j < 4; ++j) {
            float4 v = p[j];
            w[4*j+0] = v.x; w[4*j+1] = v.y; w[4*j+2] = v.z; w[4*j+3] = v.w;
        }
    } else {
        #pragma unroll
        for (int j = 0; j < 16; ++j) w[j] = reflect_load(rp, o - 4 + j, L);
    }
    float s5 = w[2] + w[3] + w[4] + w[5] + w[6];
    #pragma unroll
    for (int k = 0; k < EPT; ++k) {
        float r = w[4 + k] - s5 * 0.2f;
        s += (double)r;
        s2 = fma((double)r, (double)r, s2);
        if (k < EPT - 1) s5 += w[7 + k] - w[2 + k];
    }
}

__device__ __forceinline__ void chunkB(const float* __restrict__ rp, int o, int L,
                                       float t1, double& s, double& s2) {
    float xv[12];   // xp1 at logical [o-2, o+10)
    if (o >= 8 && o + 16 <= L) {
        float w[24];   // x[o-8 .. o+15]
        const float4* p = reinterpret_cast<const float4*>(rp + o - 8);
        #pragma unroll
        for (int j = 0; j < 6; ++j) {
            float4 v = p[j];
            w[4*j+0] = v.x; w[4*j+1] = v.y; w[4*j+2] = v.z; w[4*j+3] = v.w;
        }
        float s5  = w[4] + w[5] + w[6] + w[7] + w[8];
        float s11 = w[1] + w[2] + w[3] + w[4] + w[5] + w[6]
                  + w[7] + w[8] + w[9] + w[10] + w[11];
        #pragma unroll
        for (int j = 0; j < 12; ++j) {
            float local = s5 * 0.2f;
            float trend = s11 * (1.0f / 11.0f);
            float r = w[6 + j] - local;
            r = (fabsf(r) > t1) ? r * C_SPIKE_D : r;
            xv[j] = (1.0f - C_TREND) * local + C_TREND * trend + C_DETAIL * r;
            if (j < 11) { s5 += w[9 + j] - w[4 + j]; s11 += w[12 + j] - w[1 + j]; }
        }
    } else {
        #pragma unroll
        for (int j = 0; j < 12; ++j) xv[j] = xp1_scalar(rp, L, o - 2 + j, t1);
    }
    float t5 = xv[0] + xv[1] + xv[2] + xv[3] + xv[4];
    #pragma unroll
    for (int k = 0; k < EPT; ++k) {
        float r2 = xv[2 + k] - t5 * 0.2f;
        s += (double)r2;
        s2 = fma((double)r2, (double)r2, s2);
        if (k < EPT - 1) t5 += xv[5 + k] - xv[k];
    }
}

__device__ __forceinline__ void chunkC(const float* __restrict__ rp, float* __restrict__ orow,
                                       int o, int L, float t1, float t2) {
    float xv[18];   // xp1 at logical [o-5, o+13)
    if (o >= 12 && o + 20 <= L) {
        float w[32];   // x[o-12 .. o+19]
        const float4* p = reinterpret_cast<const float4*>(rp + o - 12);
        #pragma unroll
        for (int j = 0; j < 8; ++j) {
            float4 v = p[j];
            w[4*j+0] = v.x; w[4*j+1] = v.y; w[4*j+2] = v.z; w[4*j+3] = v.w;
        }
        float s5  = w[5] + w[6] + w[7] + w[8] + w[9];
        float s11 = w[2] + w[3] + w[4] + w[5] + w[6] + w[7]
                  + w[8] + w[9] + w[10] + w[11] + w[12];
        #pragma unroll
        for (int j = 0; j < 18; ++j) {
            float local = s5 * 0.2f;
            float trend = s11 * (1.0f / 11.0f);
            float r = w[7 + j] - local;
            r = (fabsf(r) > t1) ? r * C_SPIKE_D : r;
            xv[j] = (1.0f - C_TREND) * local + C_TREND * trend + C_DETAIL * r;
            if (j < 17) { s5 += w[10 + j] - w[5 + j]; s11 += w[13 + j] - w[2 + j]; }
        }
    } else {
        #pragma unroll
        for (int j = 0; j < 18; ++j) xv[j] = xp1_scalar(rp, L, o - 5 + j, t1);
    }
    float s5  = xv[3] + xv[4] + xv[5] + xv[6] + xv[7];
    float s11 = xv[0] + xv[1] + xv[2] + xv[3] + xv[4] + xv[5]
              + xv[6] + xv[7] + xv[8] + xv[9] + xv[10];
    float res[EPT];
    #pragma unroll
    for (int k = 0; k < EPT; ++k) {
        float local = s5 * 0.2f;
        float trend = s11 * (1.0f / 11.0f);
        float r = xv[5 + k] - local;
        r = (fabsf(r) > t2) ? r * C_SPIKE_D : r;
        res[k] = (1.0f - C_TREND) * local + C_TREND * trend + C_DETAIL * r;
        if (k < EPT - 1) { s5 += xv[8 + k] - xv[3 + k]; s11 += xv[11 + k] - xv[k]; }
    }
    vfloat4 r0 = { res[0], res[1], res[2], res[3] };
    vfloat4 r1 = { res[4], res[5], res[6], res[7] };
    __builtin_nontemporal_store(r0, reinterpret_cast<vfloat4*>(orow + o));
    __builtin_nontemporal_store(r1, reinterpret_cast<vfloat4*>(orow + o) + 1);
}

// ================= single cooperative kernel =================
__global__ __launch_bounds__(NTHREADS) void fractal_coop(
    const float* __restrict__ x, float* __restrict__ out,
    double* __restrict__ p1, double* __restrict__ p2, int L) {
    cg::grid_group grid = cg::this_grid();
    int row  = blockIdx.x / BPRB_C;
    int cgid = blockIdx.x % BPRB_C;
    int cpb  = (L / CHUNK) / BPRB_C;    // 16
    const float* rp = x + (size_t)row * L;
    float* orow = out + (size_t)row * L;
    int base = cgid * cpb;

    // Phase A: pass-1 residual partials
    {
        double s = 0.0, s2 = 0.0;
        for (int i = 0; i < cpb; ++i)
            chunkA(rp, (base + i) * CHUNK + threadIdx.x * EPT, L, s, s2);
        blk_reduce2(s, s2);
        if (threadIdx.x == 0) {
            __hip_atomic_store(p1 + 2*blockIdx.x + 0, s,  __ATOMIC_RELAXED, __HIP_MEMORY_SCOPE_AGENT);
            __hip_atomic_store(p1 + 2*blockIdx.x + 1, s2, __ATOMIC_RELAXED, __HIP_MEMORY_SCOPE_AGENT);
        }
    }
    grid.sync();

    float t1 = compute_thr<BPRB_C, true>(p1 + row * 2 * BPRB_C, L);

    // Phase B: pass-2 residual partials (xp1 recomputed in-register)
    {
        double s = 0.0, s2 = 0.0;
        for (int i = 0; i < cpb; ++i)
            chunkB(rp, (base + i) * CHUNK + threadIdx.x * EPT, L, t1, s, s2);
        blk_reduce2(s, s2);
        if (threadIdx.x == 0) {
            __hip_atomic_store(p2 + 2*blockIdx.x + 0, s,  __ATOMIC_RELAXED, __HIP_MEMORY_SCOPE_AGENT);
            __hip_atomic_store(p2 + 2*blockIdx.x + 1, s2, __ATOMIC_RELAXED, __HIP_MEMORY_SCOPE_AGENT);
        }
    }
    grid.sync();

    float t2 = compute_thr<BPRB_C, true>(p2 + row * 2 * BPRB_C, L);

    // Phase C: apply pass-2, write out
    for (int i = 0; i < cpb; ++i)
        chunkC(rp, orow, (base + i) * CHUNK + threadIdx.x * EPT, L, t1, t2);
}

// ================= fallback: R6-proven 3-kernel path =================
__global__ __launch_bounds__(NTHREADS) void k1_reduce(
    const float* __restrict__ x, double* __restrict__ partials1, int L, int cpb) {
    int row = blockIdx.x / BPRB_F, cgid = blockIdx.x % BPRB_F;
    const float* rp = x + (size_t)row * L;
    int base = cgid * cpb;
    double s = 0.0, s2 = 0.0;
    for (int i = 0; i < cpb; ++i)
        chunkA(rp, (base + i) * CHUNK + threadIdx.x * EPT, L, s, s2);
    blk_reduce2(s, s2);
    if (threadIdx.x == 0) { partials1[2*blockIdx.x] = s; partials1[2*blockIdx.x+1] = s2; }
}

__global__ __launch_bounds__(NTHREADS) void k2_reduce(
    const float* __restrict__ x, const double* __restrict__ partials1,
    double* __restrict__ partials2, int L, int cpb) {
    int row = blockIdx.x / BPRB_F, cgid = blockIdx.x % BPRB_F;
    const float* rp = x + (size_t)row * L;
    float t1 = compute_thr<BPRB_F, false>(partials1 + row * 2 * BPRB_F, L);
    int base = cgid * cpb;
    double s = 0.0, s2 = 0.0;
    for (int i = 0; i < cpb; ++i)
        chunkB(rp, (base + i) * CHUNK + threadIdx.x * EPT, L, t1, s, s2);
    blk_reduce2(s, s2);
    if (threadIdx.x == 0) { partials2[2*blockIdx.x] = s; partials2[2*blockIdx.x+1] = s2; }
}

__global__ __launch_bounds__(NTHREADS) void k3_apply(
    const float* __restrict__ x, const double* __restrict__ partials1,
    const double* __restrict__ partials2, float* __restrict__ out, int L, int cpb) {
    int row = blockIdx.x / BPRB_F, cgid = blockIdx.x % BPRB_F;
    const float* rp = x + (size_t)row * L;
    float* orow = out + (size_t)row * L;
    float t1 = compute_thr<BPRB_F, false>(partials1 + row * 2 * BPRB_F, L);
    float t2 = compute_thr<BPRB_F, false>(partials2 + row * 2 * BPRB_F, L);
    int base = cgid * cpb;
    for (int i = 0; i < cpb; ++i)
        chunkC(rp, orow, (base + i) * CHUNK + threadIdx.x * EPT, L, t1, t2);
}

extern "C" void kernel_launch(void* const* d_in, const int* in_sizes, int n_in,
                              void* d_out, int out_size, void* d_ws, size_t ws_size,
                              hipStream_t stream) {
    const float* x = (const float*)d_in[0];
    float* outp = (float*)d_out;

    int total = in_sizes[0];
    int L = total / ROWS;          // 1048576

    // workspace: [coop p1 8KB][coop p2 8KB][fb p1 16KB][fb p2 16KB]
    double* p1c = (double*)d_ws;
    double* p2c = p1c + 2 * NBLOCKS_C;
    double* p1f = p2c + 2 * NBLOCKS_C;
    double* p2f = p1f + 2 * NBLOCKS_F;

    // Cooperative path: pre-check co-residency, attempt, else fallback.
    int maxBlk = 0;
    hipError_t qe = hipOccupancyMaxActiveBlocksPerMultiprocessor(
        &maxBlk, (const void*)fractal_coop, NTHREADS, 0);
    bool coop = (qe == hipSuccess) && (maxBlk * 256 >= NBLOCKS_C);
    if (coop) {
        void* args[] = { (void*)&x, (void*)&outp, (void*)&p1c, (void*)&p2c, (void*)&L };
        coop = (hipLaunchCooperativeKernel((void*)fractal_coop, dim3(NBLOCKS_C),
                                           dim3(NTHREADS), args, 0, stream) == hipSuccess);
    }
    if (!coop) {
        int cpb = (L / CHUNK) / BPRB_F;   // 8
        k1_reduce<<<NBLOCKS_F, NTHREADS, 0, stream>>>(x, p1f, L, cpb);
        k2_reduce<<<NBLOCKS_F, NTHREADS, 0, stream>>>(x, p1f, p2f, L, cpb);
        k3_apply <<<NBLOCKS_F, NTHREADS, 0, stream>>>(x, p1f, p2f, outp, L, cpb);
    }
}

// Round 8
// 72.600 us; speedup vs baseline: 2.5343x; 2.5343x over previous
//
#include <hip/hip_runtime.h>
#include <hip/hip_cooperative_groups.h>

namespace cg = cooperative_groups;

#define NTHREADS 256
#define EPT      8              // elements per thread per chunk
#define CHUNK    (NTHREADS*EPT) // 2048 elements
#define ROWS     16
#define NBLOCKS_C 2048          // cooperative grid: 8 blocks/CU on 256 CUs
#define BPRB_C   (NBLOCKS_C/ROWS) // 128 blocks per row
#define NBLOCKS_F 1024          // fallback grid (R6-proven)
#define BPRB_F   (NBLOCKS_F/ROWS) // 64 blocks per row

#define C_TREND   0.6f
#define C_DETAIL  0.85f
#define C_SPIKE_T 3.5f
#define C_SPIKE_D 0.35f
#define C_EPS     1e-6f

typedef float vfloat4 __attribute__((ext_vector_type(4)));

__device__ __forceinline__ float reflect_load(const float* __restrict__ rp, int g, int L) {
    if (g < 0) g = -g;
    else if (g >= L) g = 2 * L - 2 - g;
    return rp[g];
}

// Deterministic block reduce of (s,s2); totals valid in ALL threads.
__device__ __forceinline__ void blk_reduce2(double& s, double& s2) {
    #pragma unroll
    for (int off = 32; off > 0; off >>= 1) {
        s  += __shfl_xor(s, off);
        s2 += __shfl_xor(s2, off);
    }
    __shared__ double lds[8];
    int wid = threadIdx.x >> 6, lane = threadIdx.x & 63;
    __syncthreads();                       // guard lds reuse
    if (lane == 0) { lds[2*wid] = s; lds[2*wid+1] = s2; }
    __syncthreads();
    s  = lds[0] + lds[2] + lds[4] + lds[6];
    s2 = lds[1] + lds[3] + lds[5] + lds[7];
}

// Deterministic variance->threshold from (s,s2) totals.
__device__ __forceinline__ float var_to_thr(double s, double s2, int L) {
    double n = (double)L;
    double var = (s2 - s * s / n) / (n - 1.0);
    float stdv = (float)sqrt(fmax(var, 0.0));
    return fmaxf(stdv, C_EPS) * C_SPIKE_T;
}

// thr from 128 (s,s2) pairs; identical value in every block (fixed order).
// Wave 0: lane l sums entries 2l,2l+1, then 64-lane butterfly.
__device__ __forceinline__ float compute_thr128(const double* __restrict__ prow, int L) {
    __shared__ float thr_s;
    __syncthreads();                       // guard thr_s reuse
    if (threadIdx.x < 64) {
        int l = threadIdx.x;
        double s  = __hip_atomic_load(prow + 4*l + 0, __ATOMIC_RELAXED, __HIP_MEMORY_SCOPE_AGENT)
                  + __hip_atomic_load(prow + 4*l + 2, __ATOMIC_RELAXED, __HIP_MEMORY_SCOPE_AGENT);
        double s2 = __hip_atomic_load(prow + 4*l + 1, __ATOMIC_RELAXED, __HIP_MEMORY_SCOPE_AGENT)
                  + __hip_atomic_load(prow + 4*l + 3, __ATOMIC_RELAXED, __HIP_MEMORY_SCOPE_AGENT);
        #pragma unroll
        for (int off = 32; off > 0; off >>= 1) {
            s  += __shfl_xor(s, off);
            s2 += __shfl_xor(s2, off);
        }
        if (threadIdx.x == 0) thr_s = var_to_thr(s, s2, L);
    }
    __syncthreads();
    return thr_s;
}

// thr from 64 (s,s2) pairs (fallback path, plain loads).
__device__ __forceinline__ float compute_thr64(const double* __restrict__ prow, int L) {
    __shared__ float thr_s;
    __syncthreads();
    if (threadIdx.x < 64) {
        double s  = prow[2*threadIdx.x + 0];
        double s2 = prow[2*threadIdx.x + 1];
        #pragma unroll
        for (int off = 32; off > 0; off >>= 1) {
            s  += __shfl_xor(s, off);
            s2 += __shfl_xor(s2, off);
        }
        if (threadIdx.x == 0) thr_s = var_to_thr(s, s2, L);
    }
    __syncthreads();
    return thr_s;
}

// scalar (boundary) pass-1 output at logical position p (reflect-indexed)
__device__ float xp1_scalar(const float* __restrict__ rp, int L, int p, float thr) {
    if (p < 0) p = -p;
    else if (p >= L) p = 2 * L - 2 - p;
    float s5 = 0.f, s11 = 0.f;
    #pragma unroll
    for (int k = -5; k <= 5; ++k) {
        float v = reflect_load(rp, p + k, L);
        s11 += v;
        if (k >= -2 && k <= 2) s5 += v;
    }
    float local = s5 * 0.2f;
    float trend = s11 * (1.0f / 11.0f);
    float r = rp[p] - local;
    r = (fabsf(r) > thr) ? r * C_SPIKE_D : r;
    return (1.0f - C_TREND) * local + C_TREND * trend + C_DETAIL * r;
}

// ---- per-chunk phase bodies (identical math to the R6-verified kernels) ----

__device__ __forceinline__ void chunkA(const float* __restrict__ rp, int o, int L,
                                       double& s, double& s2) {
    float w[16];
    if (o >= 4 && o + 12 <= L) {
        const float4* p = reinterpret_cast<const float4*>(rp + o - 4);
        #pragma unroll
        for (int j = 0; j < 4; ++j) {
            float4 v = p[j];
            w[4*j+0] = v.x; w[4*j+1] = v.y; w[4*j+2] = v.z; w[4*j+3] = v.w;
        }
    } else {
        #pragma unroll
        for (int j = 0; j < 16; ++j) w[j] = reflect_load(rp, o - 4 + j, L);
    }
    float s5 = w[2] + w[3] + w[4] + w[5] + w[6];
    #pragma unroll
    for (int k = 0; k < EPT; ++k) {
        float r = w[4 + k] - s5 * 0.2f;
        s += (double)r;
        s2 = fma((double)r, (double)r, s2);
        if (k < EPT - 1) s5 += w[7 + k] - w[2 + k];
    }
}

__device__ __forceinline__ void chunkB(const float* __restrict__ rp, int o, int L,
                                       float t1, double& s, double& s2) {
    float xv[12];   // xp1 at logical [o-2, o+10)
    if (o >= 8 && o + 16 <= L) {
        float w[24];   // x[o-8 .. o+15]
        const float4* p = reinterpret_cast<const float4*>(rp + o - 8);
        #pragma unroll
        for (int j = 0; j < 6; ++j) {
            float4 v = p[j];
            w[4*j+0] = v.x; w[4*j+1] = v.y; w[4*j+2] = v.z; w[4*j+3] = v.w;
        }
        float s5  = w[4] + w[5] + w[6] + w[7] + w[8];
        float s11 = w[1] + w[2] + w[3] + w[4] + w[5] + w[6]
                  + w[7] + w[8] + w[9] + w[10] + w[11];
        #pragma unroll
        for (int j = 0; j < 12; ++j) {
            float local = s5 * 0.2f;
            float trend = s11 * (1.0f / 11.0f);
            float r = w[6 + j] - local;
            r = (fabsf(r) > t1) ? r * C_SPIKE_D : r;
            xv[j] = (1.0f - C_TREND) * local + C_TREND * trend + C_DETAIL * r;
            if (j < 11) { s5 += w[9 + j] - w[4 + j]; s11 += w[12 + j] - w[1 + j]; }
        }
    } else {
        #pragma unroll
        for (int j = 0; j < 12; ++j) xv[j] = xp1_scalar(rp, L, o - 2 + j, t1);
    }
    float t5 = xv[0] + xv[1] + xv[2] + xv[3] + xv[4];
    #pragma unroll
    for (int k = 0; k < EPT; ++k) {
        float r2 = xv[2 + k] - t5 * 0.2f;
        s += (double)r2;
        s2 = fma((double)r2, (double)r2, s2);
        if (k < EPT - 1) t5 += xv[5 + k] - xv[k];
    }
}

__device__ __forceinline__ void chunkC(const float* __restrict__ rp, float* __restrict__ orow,
                                       int o, int L, float t1, float t2) {
    float xv[18];   // xp1 at logical [o-5, o+13)
    if (o >= 12 && o + 20 <= L) {
        float w[32];   // x[o-12 .. o+19]
        const float4* p = reinterpret_cast<const float4*>(rp + o - 12);
        #pragma unroll
        for (int j = 0; j < 8; ++j) {
            float4 v = p[j];
            w[4*j+0] = v.x; w[4*j+1] = v.y; w[4*j+2] = v.z; w[4*j+3] = v.w;
        }
        float s5  = w[5] + w[6] + w[7] + w[8] + w[9];
        float s11 = w[2] + w[3] + w[4] + w[5] + w[6] + w[7]
                  + w[8] + w[9] + w[10] + w[11] + w[12];
        #pragma unroll
        for (int j = 0; j < 18; ++j) {
            float local = s5 * 0.2f;
            float trend = s11 * (1.0f / 11.0f);
            float r = w[7 + j] - local;
            r = (fabsf(r) > t1) ? r * C_SPIKE_D : r;
            xv[j] = (1.0f - C_TREND) * local + C_TREND * trend + C_DETAIL * r;
            if (j < 17) { s5 += w[10 + j] - w[5 + j]; s11 += w[13 + j] - w[2 + j]; }
        }
    } else {
        #pragma unroll
        for (int j = 0; j < 18; ++j) xv[j] = xp1_scalar(rp, L, o - 5 + j, t1);
    }
    float s5  = xv[3] + xv[4] + xv[5] + xv[6] + xv[7];
    float s11 = xv[0] + xv[1] + xv[2] + xv[3] + xv[4] + xv[5]
              + xv[6] + xv[7] + xv[8] + xv[9] + xv[10];
    float res[EPT];
    #pragma unroll
    for (int k = 0; k < EPT; ++k) {
        float local = s5 * 0.2f;
        float trend = s11 * (1.0f / 11.0f);
        float r = xv[5 + k] - local;
        r = (fabsf(r) > t2) ? r * C_SPIKE_D : r;
        res[k] = (1.0f - C_TREND) * local + C_TREND * trend + C_DETAIL * r;
        if (k < EPT - 1) { s5 += xv[8 + k] - xv[3 + k]; s11 += xv[11 + k] - xv[k]; }
    }
    vfloat4 r0 = { res[0], res[1], res[2], res[3] };
    vfloat4 r1 = { res[4], res[5], res[6], res[7] };
    __builtin_nontemporal_store(r0, reinterpret_cast<vfloat4*>(orow + o));
    __builtin_nontemporal_store(r1, reinterpret_cast<vfloat4*>(orow + o) + 1);
}

// ================= single cooperative kernel (8 blocks/CU) =================
__global__ __launch_bounds__(NTHREADS) void fractal_coop(
    const float* __restrict__ x, float* __restrict__ out,
    double* __restrict__ p1, double* __restrict__ p2, int L) {
    cg::grid_group grid = cg::this_grid();
    int row  = blockIdx.x / BPRB_C;
    int cgid = blockIdx.x % BPRB_C;
    int cpb  = (L / CHUNK) / BPRB_C;    // 4
    const float* rp = x + (size_t)row * L;
    float* orow = out + (size_t)row * L;
    int base = cgid * cpb;

    // Phase A: pass-1 residual partials
    {
        double s = 0.0, s2 = 0.0;
        for (int i = 0; i < cpb; ++i)
            chunkA(rp, (base + i) * CHUNK + threadIdx.x * EPT, L, s, s2);
        blk_reduce2(s, s2);
        if (threadIdx.x == 0) {
            __hip_atomic_store(p1 + 2*blockIdx.x + 0, s,  __ATOMIC_RELAXED, __HIP_MEMORY_SCOPE_AGENT);
            __hip_atomic_store(p1 + 2*blockIdx.x + 1, s2, __ATOMIC_RELAXED, __HIP_MEMORY_SCOPE_AGENT);
        }
    }
    grid.sync();

    float t1 = compute_thr128(p1 + row * 2 * BPRB_C, L);

    // Phase B: pass-2 residual partials (xp1 recomputed in-register)
    {
        double s = 0.0, s2 = 0.0;
        for (int i = 0; i < cpb; ++i)
            chunkB(rp, (base + i) * CHUNK + threadIdx.x * EPT, L, t1, s, s2);
        blk_reduce2(s, s2);
        if (threadIdx.x == 0) {
            __hip_atomic_store(p2 + 2*blockIdx.x + 0, s,  __ATOMIC_RELAXED, __HIP_MEMORY_SCOPE_AGENT);
            __hip_atomic_store(p2 + 2*blockIdx.x + 1, s2, __ATOMIC_RELAXED, __HIP_MEMORY_SCOPE_AGENT);
        }
    }
    grid.sync();

    float t2 = compute_thr128(p2 + row * 2 * BPRB_C, L);

    // Phase C: apply pass-2, write out
    for (int i = 0; i < cpb; ++i)
        chunkC(rp, orow, (base + i) * CHUNK + threadIdx.x * EPT, L, t1, t2);
}

// ================= fallback: R6-proven 3-kernel path =================
__global__ __launch_bounds__(NTHREADS) void k1_reduce(
    const float* __restrict__ x, double* __restrict__ partials1, int L, int cpb) {
    int row = blockIdx.x / BPRB_F, cgid = blockIdx.x % BPRB_F;
    const float* rp = x + (size_t)row * L;
    int base = cgid * cpb;
    double s = 0.0, s2 = 0.0;
    for (int i = 0; i < cpb; ++i)
        chunkA(rp, (base + i) * CHUNK + threadIdx.x * EPT, L, s, s2);
    blk_reduce2(s, s2);
    if (threadIdx.x == 0) { partials1[2*blockIdx.x] = s; partials1[2*blockIdx.x+1] = s2; }
}

__global__ __launch_bounds__(NTHREADS) void k2_reduce(
    const float* __restrict__ x, const double* __restrict__ partials1,
    double* __restrict__ partials2, int L, int cpb) {
    int row = blockIdx.x / BPRB_F, cgid = blockIdx.x % BPRB_F;
    const float* rp = x + (size_t)row * L;
    float t1 = compute_thr64(partials1 + row * 2 * BPRB_F, L);
    int base = cgid * cpb;
    double s = 0.0, s2 = 0.0;
    for (int i = 0; i < cpb; ++i)
        chunkB(rp, (base + i) * CHUNK + threadIdx.x * EPT, L, t1, s, s2);
    blk_reduce2(s, s2);
    if (threadIdx.x == 0) { partials2[2*blockIdx.x] = s; partials2[2*blockIdx.x+1] = s2; }
}

__global__ __launch_bounds__(NTHREADS) void k3_apply(
    const float* __restrict__ x, const double* __restrict__ partials1,
    const double* __restrict__ partials2, float* __restrict__ out, int L, int cpb) {
    int row = blockIdx.x / BPRB_F, cgid = blockIdx.x % BPRB_F;
    const float* rp = x + (size_t)row * L;
    float* orow = out + (size_t)row * L;
    float t1 = compute_thr64(partials1 + row * 2 * BPRB_F, L);
    float t2 = compute_thr64(partials2 + row * 2 * BPRB_F, L);
    int base = cgid * cpb;
    for (int i = 0; i < cpb; ++i)
        chunkC(rp, orow, (base + i) * CHUNK + threadIdx.x * EPT, L, t1, t2);
}

extern "C" void kernel_launch(void* const* d_in, const int* in_sizes, int n_in,
                              void* d_out, int out_size, void* d_ws, size_t ws_size,
                              hipStream_t stream) {
    const float* x = (const float*)d_in[0];
    float* outp = (float*)d_out;

    int total = in_sizes[0];
    int L = total / ROWS;          // 1048576

    // workspace: [coop p1 32KB][coop p2 32KB][fb p1 16KB][fb p2 16KB]
    double* p1c = (double*)d_ws;
    double* p2c = p1c + 2 * NBLOCKS_C;
    double* p1f = p2c + 2 * NBLOCKS_C;
    double* p2f = p1f + 2 * NBLOCKS_F;

    // Cooperative path: require full 8 blocks/CU co-residency, else fallback.
    int maxBlk = 0;
    hipError_t qe = hipOccupancyMaxActiveBlocksPerMultiprocessor(
        &maxBlk, (const void*)fractal_coop, NTHREADS, 0);
    bool coop = (qe == hipSuccess) && (maxBlk * 256 >= NBLOCKS_C);
    if (coop) {
        void* args[] = { (void*)&x, (void*)&outp, (void*)&p1c, (void*)&p2c, (void*)&L };
        coop = (hipLaunchCooperativeKernel((void*)fractal_coop, dim3(NBLOCKS_C),
                                           dim3(NTHREADS), args, 0, stream) == hipSuccess);
    }
    if (!coop) {
        int cpb = (L / CHUNK) / BPRB_F;   // 8
        k1_reduce<<<NBLOCKS_F, NTHREADS, 0, stream>>>(x, p1f, L, cpb);
        k2_reduce<<<NBLOCKS_F, NTHREADS, 0, stream>>>(x, p1f, p2f, L, cpb);
        k3_apply <<<NBLOCKS_F, NTHREADS, 0, stream>>>(x, p1f, p2f, outp, L, cpb);
    }
}